// Round 3
// baseline (4863.675 us; speedup 1.0000x reference)
//
#include <hip/hip_runtime.h>

// Problem constants
#define S_TOTAL   256     // synapses (C*S)
#define T_IN      1000    // input time steps
#define U_TOTAL   1081    // conv output length: 1000 + 2*64 - 48 + 1
#define NEUR      64      // neurons (out channels)
#define KJ        48      // response kernel length
#define U_TILE    256     // output columns per workgroup
#define S_CHUNK   32      // synapses staged in LDS per iteration
#define WIN       320     // LDS x-window length (256 + 47 rounded up, + left margin 64)

// ---------------------------------------------------------------------------
// Kernel 1: build g-table, layout [s][j][n] (n contiguous for uniform loads).
// Replicates reference fp32 op order exactly:
//   t_spike = j/16 ;  t_leak = -(j - w*16)/32 + w ;  g = max(0, min(ts, tl))
// (all scales are powers of two -> bit-exact vs jnp)
// ---------------------------------------------------------------------------
__global__ __launch_bounds__(256) void build_gtab(const float* __restrict__ weight,
                                                  float* __restrict__ gtab) {
    int idx = blockIdx.x * 256 + threadIdx.x;        // 256*48*64 = 786432 total
    if (idx >= S_TOTAL * KJ * NEUR) return;
    int n = idx & 63;
    int j = (idx >> 6) % KJ;
    int s = idx / (NEUR * KJ);
    float w  = weight[n * S_TOTAL + s];
    float ts = (float)j * 0.0625f;                    // j/16, exact
    float tl = -(((float)j) - w * 16.0f) * 0.03125f + w;
    float g  = fmaxf(0.0f, fminf(ts, tl));
    gtab[(s * KJ + j) * NEUR + n] = g;
}

// ---------------------------------------------------------------------------
// Kernel 2: conv + fused in-register argmax epilogue.
// Grid: (5 u-tiles, 128 batches), block = 256 threads (4 waves).
// Thread tid handles output column u = u0 + tid; holds acc[64] (one per neuron).
// pot[b,n,u] = sum_{s,j} g[n,s,j] * x[b,s,u-17-j]   (x zero-padded)
// ---------------------------------------------------------------------------
__global__ __launch_bounds__(256) void conv_kernel(const float* __restrict__ x,
                                                   const float* __restrict__ gtab,
                                                   float* __restrict__ maxv,
                                                   int*   __restrict__ argn) {
    __shared__ float W[S_CHUNK][WIN];                 // 40960 B
    const int tile = blockIdx.x;                      // 0..4
    const int b    = blockIdx.y;                      // 0..127
    const int u0   = tile * U_TILE;
    const int tid  = threadIdx.x;

    float acc[NEUR];
#pragma unroll
    for (int n = 0; n < NEUR; ++n) acc[n] = 0.0f;

    const float* xb = x + (size_t)b * (S_TOTAL * T_IN);

    for (int c = 0; c < S_TOTAL / S_CHUNK; ++c) {
        const int s0 = c * S_CHUNK;
        // ---- stage x[s0..s0+31][u0-64 .. u0+255] into LDS (zero-padded) ----
        for (int idx = tid; idx < S_CHUNK * (WIN / 4); idx += 256) {
            int s  = idx / (WIN / 4);
            int q4 = idx % (WIN / 4);
            int xi = u0 - 64 + q4 * 4;                // first of 4 input times
            const float* row = xb + (s0 + s) * T_IN;
            float4 v;
            if (xi >= 0 && xi + 3 < T_IN) {
                v = *(const float4*)(row + xi);
            } else {
                v = make_float4(
                    (xi + 0 >= 0 && xi + 0 < T_IN) ? row[xi + 0] : 0.0f,
                    (xi + 1 >= 0 && xi + 1 < T_IN) ? row[xi + 1] : 0.0f,
                    (xi + 2 >= 0 && xi + 2 < T_IN) ? row[xi + 2] : 0.0f,
                    (xi + 3 >= 0 && xi + 3 < T_IN) ? row[xi + 3] : 0.0f);
            }
            *(float4*)&W[s][q4 * 4] = v;
        }
        __syncthreads();
        // ---- compute: 1 LDS read feeds 64 FMAs (g via uniform/scalar path) ----
        for (int s = 0; s < S_CHUNK; ++s) {
            const float* gp = gtab + (size_t)(s0 + s) * (KJ * NEUR);
            for (int j = 0; j < KJ; ++j) {
                float xv = W[s][tid + 47 - j];        // x[b, s0+s, u-17-j]
                const float* g = gp + j * NEUR;
#pragma unroll
                for (int n = 0; n < NEUR; ++n)
                    acc[n] = fmaf(g[n], xv, acc[n]);
            }
        }
        __syncthreads();
    }

    // ---- epilogue: pot = acc + THETA//2 ; in-register max/argmax over n ----
    const int u = u0 + tid;
    if (u < U_TOTAL) {
        float bestv = acc[0] + 10.0f;
        int   bestn = 0;
#pragma unroll
        for (int n = 1; n < NEUR; ++n) {
            float p = acc[n] + 10.0f;
            if (p > bestv) { bestv = p; bestn = n; }  // strict > keeps first max
        }
        maxv[b * U_TOTAL + u] = bestv;
        argn[b * U_TOTAL + u] = bestn;
    }
}

// ---------------------------------------------------------------------------
// Kernel 3: zero-fill output slice + sequential WTA depression scan per batch.
// One wave per b. spike <=> (dep==0 && max > THETA); then dep=48 else dep-1.
// OUTPUT IS INT32 (reference returns int32 one-hot spikes).
// ---------------------------------------------------------------------------
__global__ __launch_bounds__(64) void wta_kernel(const float* __restrict__ maxv,
                                                 const int*   __restrict__ argn,
                                                 int* __restrict__ out) {
    __shared__ float smv[U_TOTAL];
    __shared__ int   sarg[U_TOTAL];
    const int b   = blockIdx.x;
    const int tid = threadIdx.x;
    int* ob = out + (size_t)b * (NEUR * U_TOTAL);     // 69184 ints per b

    // zero-fill (d_out is poisoned before every timed call)
    int4 z4 = make_int4(0, 0, 0, 0);
    int4* o4 = (int4*)ob;
    for (int i = tid; i < (NEUR * U_TOTAL) / 4; i += 64) o4[i] = z4;

    for (int t = tid; t < U_TOTAL; t += 64) {
        smv[t]  = maxv[b * U_TOTAL + t];
        sarg[t] = argn[b * U_TOTAL + t];
    }
    __syncthreads();

    if (tid == 0) {
        int dep = 0;
        for (int t = 0; t < U_TOTAL; ++t) {
            float mv = smv[t];
            if (dep == 0) {
                if (mv > 20.0f) {                      // THETA
                    ob[sarg[t] * U_TOTAL + t] = 1;     // one-hot winner (int32)
                    dep = 48;                          // FODEP+1-1
                }
            } else {
                dep = dep - 1;
            }
        }
    }
}

// ---------------------------------------------------------------------------
extern "C" void kernel_launch(void* const* d_in, const int* in_sizes, int n_in,
                              void* d_out, int out_size, void* d_ws, size_t ws_size,
                              hipStream_t stream) {
    const float* x      = (const float*)d_in[0];   // [128,1,256,1000] spikes
    const float* weight = (const float*)d_in[1];   // [64,256]
    int* out = (int*)d_out;                        // [128,1,64,1081] int32

    float* gtab = (float*)d_ws;                    // 786432 f32
    float* maxv = gtab + (size_t)S_TOTAL * KJ * NEUR;          // 128*1081 f32
    int*   argn = (int*)(maxv + (size_t)128 * U_TOTAL);        // 128*1081 i32

    hipLaunchKernelGGL(build_gtab, dim3((S_TOTAL * KJ * NEUR + 255) / 256), dim3(256),
                       0, stream, weight, gtab);
    hipLaunchKernelGGL(conv_kernel, dim3((U_TOTAL + U_TILE - 1) / U_TILE, 128), dim3(256),
                       0, stream, x, gtab, maxv, argn);
    hipLaunchKernelGGL(wta_kernel, dim3(128), dim3(64),
                       0, stream, maxv, argn, out);
}

// Round 5
// 694.094 us; speedup vs baseline: 7.0072x; 7.0072x over previous
//
#include <hip/hip_runtime.h>

// ---------------------------------------------------------------------------
// Problem constants
#define S_TOTAL   256         // synapses
#define T_IN      1000        // input time steps
#define U_TOTAL   1081        // conv output length
#define NEUR      64
#define KJ        48          // response kernel length
#define THETA_F   20.0f
#define HALF_TH   10.0f

// i8 conv geometry
#define U_SPAN    256         // u columns per block (8 slabs of 32)
#define T_PAD     1328        // padded time rows in xT (64 left pad + 1000 + right pad)
#define B_ROWS    304         // LDS x-window rows: u-span 256 + 47 (j) + 1
#define LDS_B     (B_ROWS * 256)        // 77824 B
#define LDS_A     (3 * NEUR * 256)      // 49152 B  (3 planes x 64 n x 256 s)
#define A_JSTRIDE LDS_A                  // per-j slice in global gtab

#define OUT_PER_B (NEUR * U_TOTAL)      // 69184 ints per batch

typedef int v4i  __attribute__((ext_vector_type(4)));
typedef int v16i __attribute__((ext_vector_type(16)));

// async 16B global->LDS (wave-uniform LDS base; HW adds lane*16)
__device__ __forceinline__ void async16(const void* gsrc, void* ldsdst) {
    __builtin_amdgcn_global_load_lds(
        (const __attribute__((address_space(1))) unsigned int*)gsrc,
        (__attribute__((address_space(3))) unsigned int*)ldsdst, 16, 0, 0);
}

// ---------------------------------------------------------------------------
// Kernel 1: 3-plane i8 g-table, swizzled layout:
//   G[j][pl][n][m*16+i] = digit_pl( g(n, s=(m^(n&15))*16+i, j) )
// g = max(0, min(j/16, -(j - w*16)/32 + w)); fix = rint(g * 2^21); 7-bit digits.
// g < 1 strictly (g <= w < 1), so digits fit in [0,127].
// ---------------------------------------------------------------------------
__global__ __launch_bounds__(256) void build_gtab_i8(const float* __restrict__ weight,
                                                     char* __restrict__ gtab) {
    int idx = blockIdx.x * 256 + threadIdx.x;     // 48*3*64*256 = 2359296
    if (idx >= KJ * 3 * NEUR * 256) return;
    int i  = idx & 15;
    int m  = (idx >> 4) & 15;
    int n  = (idx >> 8) & 63;
    int pl = (idx >> 14) % 3;
    int j  = idx / (3 << 14);
    int s  = ((m ^ (n & 15)) << 4) | i;
    float w  = weight[n * S_TOTAL + s];
    float ts = (float)j * 0.0625f;
    float tl = -((float)j - w * 16.0f) * 0.03125f + w;
    float g  = fmaxf(0.0f, fminf(ts, tl));
    int fix = (int)rintf(g * 2097152.0f);          // 2^21
    fix = min(fix, 2097151);                       // safety (unreachable for w<1)
    int d = (pl == 0) ? (fix >> 14) : (pl == 1) ? ((fix >> 7) & 127) : (fix & 127);
    gtab[idx] = (char)d;
}

// ---------------------------------------------------------------------------
// Kernel 2: transpose + binarize x -> xT[b][tp][m*16+i] = x(s=(m^(tp&15))*16+i, t=tp-64)
// Zero outside t in [0,1000). Grid: (21 tp-tiles of 64, 128 b), 256 thr.
// ---------------------------------------------------------------------------
__global__ __launch_bounds__(256) void build_xT(const float* __restrict__ x,
                                                char* __restrict__ xT) {
    __shared__ __align__(16) char Xl[64][256];
    const int tid = threadIdx.x;
    const int tp0 = blockIdx.x * 64;
    const int b   = blockIdx.y;
    const float* xb = x + (size_t)b * (S_TOTAL * T_IN);
    const int s = tid;                              // one synapse row per thread
    const int t0 = tp0 - 64;
    for (int k = 0; k < 64; k += 4) {
        int t = t0 + k;
        float v0 = 0.f, v1 = 0.f, v2 = 0.f, v3 = 0.f;
        if (t >= 0 && t + 3 < T_IN) {
            float4 v = *(const float4*)(xb + s * T_IN + t);
            v0 = v.x; v1 = v.y; v2 = v.z; v3 = v.w;
        } else {
            if (t + 0 >= 0 && t + 0 < T_IN) v0 = xb[s * T_IN + t + 0];
            if (t + 1 >= 0 && t + 1 < T_IN) v1 = xb[s * T_IN + t + 1];
            if (t + 2 >= 0 && t + 2 < T_IN) v2 = xb[s * T_IN + t + 2];
            if (t + 3 >= 0 && t + 3 < T_IN) v3 = xb[s * T_IN + t + 3];
        }
        Xl[k + 0][s] = (char)(v0 > 0.5f);
        Xl[k + 1][s] = (char)(v1 > 0.5f);
        Xl[k + 2][s] = (char)(v2 > 0.5f);
        Xl[k + 3][s] = (char)(v3 > 0.5f);
    }
    __syncthreads();
    for (int g = tid; g < 64 * 16; g += 256) {
        int tl = g >> 4, m = g & 15;
        int tp = tp0 + tl;
        if (tp >= T_PAD) continue;
        int q = m ^ (tp & 15);                       // bake read-swizzle into layout
        v4i val = *(const v4i*)&Xl[tl][q * 16];
        *(v4i*)(xT + ((size_t)b * T_PAD + tp) * 256 + m * 16) = val;
    }
}

// ---------------------------------------------------------------------------
// Kernel 3: i8 MFMA conv + fused argmax.
// Block: 256 thr (4 waves), covers u in [u0, u0+256). Wave w owns u-slabs w, w+4.
// pot[n,u] = sum_{s,j} g[n,s,j] * x[s, u-17-j];  t_local = (u-u0) + 47 - j.
// A-frag: lane row n (swizzled by n&15); B-frag: lane col u (swizzled by t&15);
// tp&15 == t_local&15 because u0 % 16 == 0, so write/read swizzles cancel.
// C/D: col=u=lane&31, row n = (r&3)+8*(r>>2)+4*(lane>>5).
// ---------------------------------------------------------------------------
__global__ __launch_bounds__(256, 1) void conv_i8(const char* __restrict__ xT,
                                                  const char* __restrict__ gtab,
                                                  float* __restrict__ maxv,
                                                  int*   __restrict__ argn) {
    __shared__ __align__(16) char lds[LDS_B + LDS_A];   // 124 KiB
    char* Bl = lds;
    char* Al = lds + LDS_B;

    const int tid  = threadIdx.x;
    const int wid  = tid >> 6;
    const int lane = tid & 63;
    const int col  = lane & 31;
    const int h    = lane >> 5;
    const int tile = blockIdx.x;
    const int b    = blockIdx.y;
    const int u0   = tile * U_SPAN;

    // ---- stage B window (once per block): rows tp = u0 + [0,304) ----
    const char* xTb = xT + ((size_t)b * T_PAD + u0) * 256;
    for (int c = wid; c < LDS_B / 1024; c += 4)
        async16(xTb + c * 1024 + lane * 16, Bl + c * 1024);
    // ---- stage A slice j=0 ----
    for (int c = wid; c < LDS_A / 1024; c += 4)
        async16(gtab + c * 1024 + lane * 16, Al + c * 1024);

    v16i acc[2][2][3];
    const v16i zc = {0,0,0,0,0,0,0,0,0,0,0,0,0,0,0,0};
#pragma unroll
    for (int sl = 0; sl < 2; ++sl)
#pragma unroll
        for (int nh = 0; nh < 2; ++nh)
#pragma unroll
            for (int pl = 0; pl < 3; ++pl) acc[sl][nh][pl] = zc;

    for (int j = 0; j < KJ; ++j) {
        __syncthreads();                      // drains vmcnt -> staged data visible
        const int ta = 32 * wid + col + 47 - j;       // t_local, slab a (= wid)
        const int tb = ta + 128;                      // slab b (= wid+4)
#pragma unroll
        for (int c = 0; c < 8; ++c) {
            const int sb = c * 2 + h;                 // 16B-group index of k-slice
            v4i b0 = *(const v4i*)(Bl + ta * 256 + ((sb ^ (ta & 15)) << 4));
            v4i b1 = *(const v4i*)(Bl + tb * 256 + ((sb ^ (tb & 15)) << 4));
            const int aswz = (sb ^ (col & 15)) << 4;
#pragma unroll
            for (int pl = 0; pl < 3; ++pl) {
                v4i a0 = *(const v4i*)(Al + (pl * 64 +      col) * 256 + aswz);
                v4i a1 = *(const v4i*)(Al + (pl * 64 + 32 + col) * 256 + aswz);
                acc[0][0][pl] = __builtin_amdgcn_mfma_i32_32x32x32_i8(a0, b0, acc[0][0][pl], 0, 0, 0);
                acc[0][1][pl] = __builtin_amdgcn_mfma_i32_32x32x32_i8(a1, b0, acc[0][1][pl], 0, 0, 0);
                acc[1][0][pl] = __builtin_amdgcn_mfma_i32_32x32x32_i8(a0, b1, acc[1][0][pl], 0, 0, 0);
                acc[1][1][pl] = __builtin_amdgcn_mfma_i32_32x32x32_i8(a1, b1, acc[1][1][pl], 0, 0, 0);
            }
        }
        __syncthreads();                      // all waves done reading A_j
        if (j < KJ - 1) {
            const char* gj = gtab + (size_t)(j + 1) * A_JSTRIDE;
            for (int c = wid; c < LDS_A / 1024; c += 4)
                async16(gj + c * 1024 + lane * 16, Al + c * 1024);
        }
    }

    // ---- epilogue: combine planes, argmax over n in-register ----
#pragma unroll
    for (int sl = 0; sl < 2; ++sl) {
        float best = -3.0e38f;
        int   bestn = 0;
#pragma unroll
        for (int nh = 0; nh < 2; ++nh)
#pragma unroll
            for (int r = 0; r < 16; ++r) {
                float v = (float)acc[sl][nh][0][r] * 0.0078125f
                        + (float)acc[sl][nh][1][r] * 6.103515625e-05f
                        + (float)acc[sl][nh][2][r] * 4.76837158203125e-07f;
                int n = nh * 32 + (r & 3) + 8 * (r >> 2) + 4 * h;
                if (v > best || (v == best && n < bestn)) { best = v; bestn = n; }
            }
        float ov = __shfl_xor(best, 32);
        int   on = __shfl_xor(bestn, 32);
        if (ov > best || (ov == best && on < bestn)) { best = ov; bestn = on; }
        const int u = u0 + 32 * (wid + 4 * sl) + col;
        if (h == 0 && u < U_TOTAL) {
            maxv[b * U_TOTAL + u] = best + HALF_TH;
            argn[b * U_TOTAL + u] = bestn;
        }
    }
}

// ---------------------------------------------------------------------------
// Kernel 4: grid-stride zero-fill of the int32 output (poisoned before every call).
// ---------------------------------------------------------------------------
__global__ __launch_bounds__(256) void zero_out(int* __restrict__ out, int n4) {
    int4 z4 = make_int4(0, 0, 0, 0);
    int4* o4 = (int4*)out;
    int stride = gridDim.x * 256;
    for (int i = blockIdx.x * 256 + threadIdx.x; i < n4; i += stride) o4[i] = z4;
}

// ---------------------------------------------------------------------------
// Kernel 5: sequential WTA depression scan per batch; writes only the spikes.
// ---------------------------------------------------------------------------
__global__ __launch_bounds__(64) void wta_kernel(const float* __restrict__ maxv,
                                                 const int*   __restrict__ argn,
                                                 int* __restrict__ out) {
    __shared__ float smv[U_TOTAL];
    __shared__ int   sarg[U_TOTAL];
    const int b   = blockIdx.x;
    const int tid = threadIdx.x;
    int* ob = out + (size_t)b * OUT_PER_B;

    for (int t = tid; t < U_TOTAL; t += 64) {
        smv[t]  = maxv[b * U_TOTAL + t];
        sarg[t] = argn[b * U_TOTAL + t];
    }
    __syncthreads();

    if (tid == 0) {
        int dep = 0;
        for (int t = 0; t < U_TOTAL; ++t) {
            if (dep == 0) {
                if (smv[t] > THETA_F) {
                    ob[sarg[t] * U_TOTAL + t] = 1;
                    dep = 48;
                }
            } else {
                dep = dep - 1;
            }
        }
    }
}

// ---------------------------------------------------------------------------
extern "C" void kernel_launch(void* const* d_in, const int* in_sizes, int n_in,
                              void* d_out, int out_size, void* d_ws, size_t ws_size,
                              hipStream_t stream) {
    const float* x      = (const float*)d_in[0];   // [128,1,256,1000]
    const float* weight = (const float*)d_in[1];   // [64,256]
    int* out = (int*)d_out;                        // [128,1,64,1081] int32

    char*  ws   = (char*)d_ws;
    char*  xT   = ws;                                          // 43,515,904 B
    char*  gtab = ws + (size_t)128 * T_PAD * 256;              //  2,359,296 B
    float* maxv = (float*)(gtab + (size_t)KJ * 3 * NEUR * 256);
    int*   argn = (int*)((char*)maxv + (size_t)128 * U_TOTAL * 4);

    hipLaunchKernelGGL(build_gtab_i8, dim3((KJ * 3 * NEUR * 256) / 256), dim3(256),
                       0, stream, weight, gtab);
    hipLaunchKernelGGL(build_xT, dim3((T_PAD + 63) / 64, 128), dim3(256),
                       0, stream, x, xT);
    hipLaunchKernelGGL(zero_out, dim3(2048), dim3(256),
                       0, stream, out, (128 * OUT_PER_B) / 4);
    hipLaunchKernelGGL(conv_i8, dim3((U_TOTAL + U_SPAN - 1) / U_SPAN, 128), dim3(256),
                       0, stream, xT, gtab, maxv, argn);
    hipLaunchKernelGGL(wta_kernel, dim3(128), dim3(64),
                       0, stream, maxv, argn, out);
}

// Round 7
// 487.517 us; speedup vs baseline: 9.9764x; 1.4237x over previous
//
#include <hip/hip_runtime.h>

// ---------------------------------------------------------------------------
// Problem constants
#define S_TOTAL   256         // synapses
#define T_IN      1000        // input time steps
#define U_TOTAL   1081        // conv output length
#define NEUR      64
#define KJ        48          // response kernel length
#define THETA_F   20.0f
#define HALF_TH   10.0f

// i8 conv geometry
#define U_SPAN    256         // u columns per block (8 slabs of 32)
#define T_PAD     1328        // padded time rows in xT (64 left pad + 1000 + right)
#define B_ROWS    304         // LDS x-window rows: 256 + 47 + 1
#define LDS_B     (B_ROWS * 256)        // 77824 B
#define LDS_A     (2 * NEUR * 256)      // 32768 B per buffer (2 planes x 64 n x 256 s)
#define A_JSTRIDE LDS_A                  // per-j slice stride in global gtab

#define OUT_PER_B (NEUR * U_TOTAL)      // 69184 ints per batch

typedef int v4i  __attribute__((ext_vector_type(4)));
typedef int v16i __attribute__((ext_vector_type(16)));

// async 16B global->LDS (wave-uniform LDS base; HW adds lane*16)
__device__ __forceinline__ void async16(const void* gsrc, void* ldsdst) {
    __builtin_amdgcn_global_load_lds(
        (const __attribute__((address_space(1))) unsigned int*)gsrc,
        (__attribute__((address_space(3))) unsigned int*)ldsdst, 16, 0, 0);
}

// ---------------------------------------------------------------------------
// Kernel 1: 2-plane i8 g-table, swizzled layout:
//   G[j][pl][n][m*16+i] = digit_pl( g(n, s=(m^(n&15))*16+i, j) )
// g = max(0, min(j/16, -(j - w*16)/32 + w)); fix = rint(g * 2^14); 7-bit digits.
// g < 1 strictly, so fix <= 16384 -> clamp 16383 keeps digits in [0,127].
// ---------------------------------------------------------------------------
__global__ __launch_bounds__(256) void build_gtab_i8(const float* __restrict__ weight,
                                                     char* __restrict__ gtab) {
    int idx = blockIdx.x * 256 + threadIdx.x;     // 48*2*64*256 = 1572864
    if (idx >= KJ * 2 * NEUR * 256) return;
    int i  = idx & 15;
    int m  = (idx >> 4) & 15;
    int n  = (idx >> 8) & 63;
    int pl = (idx >> 14) & 1;
    int j  = idx >> 15;
    int s  = ((m ^ (n & 15)) << 4) | i;
    float w  = weight[n * S_TOTAL + s];
    float ts = (float)j * 0.0625f;
    float tl = -((float)j - w * 16.0f) * 0.03125f + w;
    float g  = fmaxf(0.0f, fminf(ts, tl));
    int fix = (int)rintf(g * 16384.0f);            // 2^14
    fix = min(fix, 16383);
    int d = pl ? (fix & 127) : (fix >> 7);
    gtab[idx] = (char)d;
}

// ---------------------------------------------------------------------------
// Kernel 2: transpose + binarize x -> xT[b][tp][m*16+i] = x(s=(m^(tp&15))*16+i, t=tp-64)
// Coalesced: 16 lanes cover one s-row's 64 t's (256 B contiguous per row-group).
// LDS float tile with +1 pad breaks the transpose bank conflict.
// ---------------------------------------------------------------------------
__global__ __launch_bounds__(256) void build_xT(const float* __restrict__ x,
                                                char* __restrict__ xT) {
    __shared__ float Xl[64][257];                  // 65792 B
    const int tid = threadIdx.x;
    const int tp0 = blockIdx.x * 64;
    const int b   = blockIdx.y;
    const float* xb = x + (size_t)b * (S_TOTAL * T_IN);
    const int t0 = tp0 - 64;
    const int lane16 = tid & 15;
    const int srow   = tid >> 4;
    const int t = t0 + lane16 * 4;                 // chunks never straddle [0,1000)
    const bool in = (t >= 0) && (t + 3 < T_IN);
#pragma unroll
    for (int pass = 0; pass < 16; ++pass) {
        int s = pass * 16 + srow;
        float4 v = make_float4(0.f, 0.f, 0.f, 0.f);
        if (in) v = *(const float4*)(xb + s * T_IN + t);
        int k = lane16 * 4;
        Xl[k + 0][s] = v.x; Xl[k + 1][s] = v.y;
        Xl[k + 2][s] = v.z; Xl[k + 3][s] = v.w;
    }
    __syncthreads();
    for (int g2 = tid; g2 < 64 * 16; g2 += 256) {
        int tl = g2 >> 4, m = g2 & 15;
        int tp = tp0 + tl;
        if (tp >= T_PAD) continue;
        int q = m ^ (tp & 15);                     // bake read-swizzle into layout
        int wds[4];
#pragma unroll
        for (int wq = 0; wq < 4; ++wq) {
            int b0 = (Xl[tl][q * 16 + wq * 4 + 0] > 0.5f) ? 1 : 0;
            int b1 = (Xl[tl][q * 16 + wq * 4 + 1] > 0.5f) ? 1 : 0;
            int b2 = (Xl[tl][q * 16 + wq * 4 + 2] > 0.5f) ? 1 : 0;
            int b3 = (Xl[tl][q * 16 + wq * 4 + 3] > 0.5f) ? 1 : 0;
            wds[wq] = b0 | (b1 << 8) | (b2 << 16) | (b3 << 24);
        }
        v4i val = { wds[0], wds[1], wds[2], wds[3] };
        *(v4i*)(xT + ((size_t)b * T_PAD + tp) * 256 + m * 16) = val;
    }
}

// ---------------------------------------------------------------------------
// Kernel 3: i8 MFMA conv + fused argmax, 2 planes, double-buffered A.
// Block: 256 thr (4 waves), u in [u0, u0+256). Wave w owns u-slabs w, w+4.
// One barrier per j; A[j+1] prefetch issued right after the barrier so it has
// a full j-iteration of compute to land before the next barrier's vmcnt drain.
// ---------------------------------------------------------------------------
__global__ __launch_bounds__(256, 1) void conv_i8(const char* __restrict__ xT,
                                                  const char* __restrict__ gtab,
                                                  float* __restrict__ maxv,
                                                  int*   __restrict__ argn) {
    __shared__ __align__(16) char lds[LDS_B + 2 * LDS_A];   // 143360 B
    char* Bl = lds;

    const int tid  = threadIdx.x;
    const int wid  = tid >> 6;
    const int lane = tid & 63;
    const int col  = lane & 31;
    const int h    = lane >> 5;
    const int tile = blockIdx.x;
    const int b    = blockIdx.y;
    const int u0   = tile * U_SPAN;

    // ---- stage B window (once per block): rows tp = u0 + [0,304) ----
    const char* xTb = xT + ((size_t)b * T_PAD + u0) * 256;
    for (int c = wid; c < LDS_B / 1024; c += 4)
        async16(xTb + c * 1024 + lane * 16, Bl + c * 1024);
    // ---- stage A slice j=0 into buffer 0 ----
    for (int c = wid; c < LDS_A / 1024; c += 4)
        async16(gtab + c * 1024 + lane * 16, lds + LDS_B + c * 1024);

    v16i acc[2][2][2];                 // [u-slab][n-half][plane]
    const v16i zc = {0,0,0,0,0,0,0,0,0,0,0,0,0,0,0,0};
#pragma unroll
    for (int sl = 0; sl < 2; ++sl)
#pragma unroll
        for (int nh = 0; nh < 2; ++nh)
#pragma unroll
            for (int pl = 0; pl < 2; ++pl) acc[sl][nh][pl] = zc;

    for (int j = 0; j < KJ; ++j) {
        __syncthreads();               // implicit vmcnt drain: A[j] (and B) landed
        // prefetch A[j+1] into the other buffer (read by no one this iteration)
        if (j < KJ - 1) {
            const char* gj = gtab + (size_t)(j + 1) * A_JSTRIDE;
            char* Ad = lds + LDS_B + ((j + 1) & 1) * LDS_A;
            for (int c = wid; c < LDS_A / 1024; c += 4)
                async16(gj + c * 1024 + lane * 16, Ad + c * 1024);
        }
        const char* Ab = lds + LDS_B + (j & 1) * LDS_A;
        const int ta = 32 * wid + col + 47 - j;        // t_local, slab a (= wid)
        const int tb = ta + 128;                       // slab b (= wid+4)
#pragma unroll
        for (int c = 0; c < 8; ++c) {
            const int sb = c * 2 + h;                  // 16B-group of the K slice
            v4i b0 = *(const v4i*)(Bl + ta * 256 + ((sb ^ (ta & 15)) << 4));
            v4i b1 = *(const v4i*)(Bl + tb * 256 + ((sb ^ (tb & 15)) << 4));
            const int aswz = (sb ^ (col & 15)) << 4;
#pragma unroll
            for (int pl = 0; pl < 2; ++pl) {
                v4i a0 = *(const v4i*)(Ab + (pl * 64 +      col) * 256 + aswz);
                v4i a1 = *(const v4i*)(Ab + (pl * 64 + 32 + col) * 256 + aswz);
                acc[0][0][pl] = __builtin_amdgcn_mfma_i32_32x32x32_i8(a0, b0, acc[0][0][pl], 0, 0, 0);
                acc[0][1][pl] = __builtin_amdgcn_mfma_i32_32x32x32_i8(a1, b0, acc[0][1][pl], 0, 0, 0);
                acc[1][0][pl] = __builtin_amdgcn_mfma_i32_32x32x32_i8(a0, b1, acc[1][0][pl], 0, 0, 0);
                acc[1][1][pl] = __builtin_amdgcn_mfma_i32_32x32x32_i8(a1, b1, acc[1][1][pl], 0, 0, 0);
            }
        }
    }

    // ---- epilogue: combine planes, argmax over n in-register ----
#pragma unroll
    for (int sl = 0; sl < 2; ++sl) {
        float best = -3.0e38f;
        int   bestn = 0;
#pragma unroll
        for (int nh = 0; nh < 2; ++nh)
#pragma unroll
            for (int r = 0; r < 16; ++r) {
                float v = (float)acc[sl][nh][0][r] * 0.0078125f          // 2^-7
                        + (float)acc[sl][nh][1][r] * 6.103515625e-05f;   // 2^-14
                int n = nh * 32 + (r & 3) + 8 * (r >> 2) + 4 * h;
                if (v > best || (v == best && n < bestn)) { best = v; bestn = n; }
            }
        float ov = __shfl_xor(best, 32);
        int   on = __shfl_xor(bestn, 32);
        if (ov > best || (ov == best && on < bestn)) { best = ov; bestn = on; }
        const int u = u0 + 32 * (wid + 4 * sl) + col;
        if (h == 0 && u < U_TOTAL) {
            maxv[b * U_TOTAL + u] = best + HALF_TH;
            argn[b * U_TOTAL + u] = bestn;
        }
    }
}

// ---------------------------------------------------------------------------
// Kernel 4: grid-stride zero-fill of the int32 output (poisoned before every call).
// ---------------------------------------------------------------------------
__global__ __launch_bounds__(256) void zero_out(int* __restrict__ out, int n4) {
    int4 z4 = make_int4(0, 0, 0, 0);
    int4* o4 = (int4*)out;
    int stride = gridDim.x * 256;
    for (int i = blockIdx.x * 256 + threadIdx.x; i < n4; i += stride) o4[i] = z4;
}

// ---------------------------------------------------------------------------
// Kernel 5: sequential WTA depression scan per batch; writes only the spikes.
// ---------------------------------------------------------------------------
__global__ __launch_bounds__(64) void wta_kernel(const float* __restrict__ maxv,
                                                 const int*   __restrict__ argn,
                                                 int* __restrict__ out) {
    __shared__ float smv[U_TOTAL];
    __shared__ int   sarg[U_TOTAL];
    const int b   = blockIdx.x;
    const int tid = threadIdx.x;
    int* ob = out + (size_t)b * OUT_PER_B;

    for (int t = tid; t < U_TOTAL; t += 64) {
        smv[t]  = maxv[b * U_TOTAL + t];
        sarg[t] = argn[b * U_TOTAL + t];
    }
    __syncthreads();

    if (tid == 0) {
        int dep = 0;
        for (int t = 0; t < U_TOTAL; ++t) {
            if (dep == 0) {
                if (smv[t] > THETA_F) {
                    ob[sarg[t] * U_TOTAL + t] = 1;
                    dep = 48;
                }
            } else {
                dep = dep - 1;
            }
        }
    }
}

// ---------------------------------------------------------------------------
extern "C" void kernel_launch(void* const* d_in, const int* in_sizes, int n_in,
                              void* d_out, int out_size, void* d_ws, size_t ws_size,
                              hipStream_t stream) {
    const float* x      = (const float*)d_in[0];   // [128,1,256,1000]
    const float* weight = (const float*)d_in[1];   // [64,256]
    int* out = (int*)d_out;                        // [128,1,64,1081] int32

    char*  ws   = (char*)d_ws;
    char*  xT   = ws;                                          // 43,515,904 B
    char*  gtab = ws + (size_t)128 * T_PAD * 256;              //  1,572,864 B
    float* maxv = (float*)(gtab + (size_t)KJ * 2 * NEUR * 256);
    int*   argn = (int*)((char*)maxv + (size_t)128 * U_TOTAL * 4);

    hipLaunchKernelGGL(build_gtab_i8, dim3((KJ * 2 * NEUR * 256) / 256), dim3(256),
                       0, stream, weight, gtab);
    hipLaunchKernelGGL(build_xT, dim3((T_PAD + 63) / 64, 128), dim3(256),
                       0, stream, x, xT);
    hipLaunchKernelGGL(zero_out, dim3(2048), dim3(256),
                       0, stream, out, (128 * OUT_PER_B) / 4);
    hipLaunchKernelGGL(conv_i8, dim3((U_TOTAL + U_SPAN - 1) / U_SPAN, 128), dim3(256),
                       0, stream, xT, gtab, maxv, argn);
    hipLaunchKernelGGL(wta_kernel, dim3(128), dim3(64),
                       0, stream, maxv, argn, out);
}

// Round 9
// 404.521 us; speedup vs baseline: 12.0233x; 1.2052x over previous
//
#include <hip/hip_runtime.h>

// ---------------------------------------------------------------------------
// Problem constants
#define S_TOTAL   256         // synapses
#define T_IN      1000        // input time steps
#define U_TOTAL   1081        // conv output length
#define NEUR      64
#define KJ        48          // response kernel length
#define THETA_F   20.0f
#define HALF_TH   10.0f

// i8 conv geometry
#define U_SPAN    256         // u columns per block (8 slabs of 32)
#define T_PAD     1328        // padded time rows in xT
#define XROW      40          // bytes per bit-packed row (32 data + 8 pad)
#define LDS_BB    12288       // staged B bits (304*40=12160, rounded to 12 KiB)
#define LDS_A     (2 * NEUR * 256)      // 32768 B per buffer (2 planes x 64 n x 256 s)
#define A_JSTRIDE LDS_A

#define OUT_PER_B (NEUR * U_TOTAL)      // 69184 ints per batch

typedef int v4i  __attribute__((ext_vector_type(4)));
typedef int v16i __attribute__((ext_vector_type(16)));

// async 16B global->LDS (wave-uniform LDS base; HW adds lane*16)
__device__ __forceinline__ void async16(const void* gsrc, void* ldsdst) {
    __builtin_amdgcn_global_load_lds(
        (const __attribute__((address_space(1))) unsigned int*)gsrc,
        (__attribute__((address_space(3))) unsigned int*)ldsdst, 16, 0, 0);
}

// expand 16 bits -> 16 i8 lanes (4 dwords), byte z of dword q = bit (4q+z)
__device__ __forceinline__ v4i expand16(unsigned int n16) {
    v4i r;
    r[0] = (int)((((n16      ) & 15u) * 0x00204081u) & 0x01010101u);
    r[1] = (int)((((n16 >> 4 ) & 15u) * 0x00204081u) & 0x01010101u);
    r[2] = (int)((((n16 >> 8 ) & 15u) * 0x00204081u) & 0x01010101u);
    r[3] = (int)((((n16 >> 12) & 15u) * 0x00204081u) & 0x01010101u);
    return r;
}

// ---------------------------------------------------------------------------
// Kernel 1: 2-plane i8 g-table, swizzled layout (unchanged from passing run):
//   G[j][pl][n][m*16+i] = digit_pl( g(n, s=(m^(n&15))*16+i, j) )
// ---------------------------------------------------------------------------
__global__ __launch_bounds__(256) void build_gtab_i8(const float* __restrict__ weight,
                                                     char* __restrict__ gtab) {
    int idx = blockIdx.x * 256 + threadIdx.x;     // 48*2*64*256 = 1572864
    if (idx >= KJ * 2 * NEUR * 256) return;
    int i  = idx & 15;
    int m  = (idx >> 4) & 15;
    int n  = (idx >> 8) & 63;
    int pl = (idx >> 14) & 1;
    int j  = idx >> 15;
    int s  = ((m ^ (n & 15)) << 4) | i;
    float w  = weight[n * S_TOTAL + s];
    float ts = (float)j * 0.0625f;
    float tl = -((float)j - w * 16.0f) * 0.03125f + w;
    float g  = fmaxf(0.0f, fminf(ts, tl));
    int fix = (int)rintf(g * 16384.0f);            // 2^14
    fix = min(fix, 16383);
    int d = pl ? (fix & 127) : (fix >> 7);
    gtab[idx] = (char)d;
}

// ---------------------------------------------------------------------------
// Kernel 2: transpose + binarize + BIT-PACK:
//   xT[b][tp] = 32-byte bitvector, bit index s = x(s, t=tp-64) > 0.5
// 32 tp-rows per block; Xl float tile stride 324 (16B-aligned rows, low conflict).
// Logical float col(s) = 20*(s>>4) + (s&15)  (group stride 20 spreads banks).
// ---------------------------------------------------------------------------
__global__ __launch_bounds__(256) void build_xT(const float* __restrict__ x,
                                                char* __restrict__ xT) {
    __shared__ float Xl[32][324];                  // 41472 B
    const int tid = threadIdx.x;
    const int tp0 = blockIdx.x * 32;
    const int b   = blockIdx.y;
    const float* xb = x + (size_t)b * (S_TOTAL * T_IN);
    const int t0 = tp0 - 64;
    const int lane8 = tid & 7;                     // t-chunk within tile
    const int srow  = tid >> 3;                    // 0..31
    const int t = t0 + lane8 * 4;                  // 4-aligned: never straddles [0,1000)
    const bool in = (t >= 0) && (t + 3 < T_IN);
#pragma unroll
    for (int pass = 0; pass < 8; ++pass) {
        int s = pass * 32 + srow;
        float4 v = make_float4(0.f, 0.f, 0.f, 0.f);
        if (in) v = *(const float4*)(xb + s * T_IN + t);
        int colv = 20 * (s >> 4) + (s & 15);
        int k = lane8 * 4;
        Xl[k + 0][colv] = v.x; Xl[k + 1][colv] = v.y;
        Xl[k + 2][colv] = v.z; Xl[k + 3][colv] = v.w;
    }
    __syncthreads();
    {
        const int tl = tid >> 3;                   // 0..31 rows
        const int dw = tid & 7;                    // 0..7 dwords (32 s each)
        const int tp = tp0 + tl;
        if (tp < T_PAD) {
            unsigned bits = 0u;
#pragma unroll
            for (int gg = 0; gg < 2; ++gg) {
                int g = 2 * dw + gg;
#pragma unroll
                for (int q = 0; q < 4; ++q) {
                    float4 f = *(const float4*)&Xl[tl][20 * g + 4 * q];
                    int z = gg * 16 + 4 * q;
                    bits |= (f.x > 0.5f ? 1u : 0u) << (z + 0);
                    bits |= (f.y > 0.5f ? 1u : 0u) << (z + 1);
                    bits |= (f.z > 0.5f ? 1u : 0u) << (z + 2);
                    bits |= (f.w > 0.5f ? 1u : 0u) << (z + 3);
                }
            }
            *(unsigned*)(xT + ((size_t)b * T_PAD + tp) * XROW + 4 * dw) = bits;
        }
    }
}

// ---------------------------------------------------------------------------
// Kernel 3: i8 MFMA conv + fused argmax. Bit-packed B in LDS (12 KiB) ->
// 77.8 KiB LDS/block -> 2 blocks/CU (launch_bounds(256,2)) -> cross-block
// overlap hides ds_read + barrier latency. A double-buffer unchanged.
// ---------------------------------------------------------------------------
__global__ __launch_bounds__(256, 2) void conv_i8(const char* __restrict__ xT,
                                                  const char* __restrict__ gtab,
                                                  float* __restrict__ maxv,
                                                  int*   __restrict__ argn) {
    __shared__ __align__(16) char lds[LDS_BB + 2 * LDS_A];   // 77824 B
    char* Bl = lds;

    const int tid  = threadIdx.x;
    const int wid  = tid >> 6;
    const int lane = tid & 63;
    const int col  = lane & 31;
    const int h    = lane >> 5;
    const int tile = blockIdx.x;
    const int b    = blockIdx.y;
    const int u0   = tile * U_SPAN;

    // ---- stage bit-packed B window: rows tp = u0 + [0,307) (12 KiB) ----
    const char* xTb = xT + ((size_t)b * T_PAD + u0) * XROW;
    for (int c = wid; c < LDS_BB / 1024; c += 4)
        async16(xTb + c * 1024 + lane * 16, Bl + c * 1024);
    // ---- stage A slice j=0 into buffer 0 ----
    for (int c = wid; c < LDS_A / 1024; c += 4)
        async16(gtab + c * 1024 + lane * 16, lds + LDS_BB + c * 1024);

    v16i acc[2][2][2];                 // [u-slab][n-half][plane]
    const v16i zc = {0,0,0,0,0,0,0,0,0,0,0,0,0,0,0,0};
#pragma unroll
    for (int sl = 0; sl < 2; ++sl)
#pragma unroll
        for (int nh = 0; nh < 2; ++nh)
#pragma unroll
            for (int pl = 0; pl < 2; ++pl) acc[sl][nh][pl] = zc;

    for (int j = 0; j < KJ; ++j) {
        __syncthreads();               // A[j] + B staged (vmcnt drained by barrier)
        if (j < KJ - 1) {              // prefetch A[j+1] into the idle buffer
            const char* gj = gtab + (size_t)(j + 1) * A_JSTRIDE;
            char* Ad = lds + LDS_BB + ((j + 1) & 1) * LDS_A;
            for (int c = wid; c < LDS_A / 1024; c += 4)
                async16(gj + c * 1024 + lane * 16, Ad + c * 1024);
        }
        const char* Ab = lds + LDS_BB + (j & 1) * LDS_A;
        const int ta = 32 * wid + col + 47 - j;        // t_local, slab a (= wid)
        const int tb = ta + 128;                       // slab b (= wid+4)
#pragma unroll
        for (int c = 0; c < 8; ++c) {
            const int sb = c * 2 + h;                  // logical 16-s k-group
            unsigned ba = *(const unsigned short*)(Bl + ta * XROW + sb * 2);
            unsigned bb = *(const unsigned short*)(Bl + tb * XROW + sb * 2);
            v4i b0 = expand16(ba);
            v4i b1 = expand16(bb);
            const int aswz = (sb ^ (col & 15)) << 4;   // A keeps its self-canceling swizzle
#pragma unroll
            for (int pl = 0; pl < 2; ++pl) {
                v4i a0 = *(const v4i*)(Ab + (pl * 64 +      col) * 256 + aswz);
                v4i a1 = *(const v4i*)(Ab + (pl * 64 + 32 + col) * 256 + aswz);
                acc[0][0][pl] = __builtin_amdgcn_mfma_i32_32x32x32_i8(a0, b0, acc[0][0][pl], 0, 0, 0);
                acc[0][1][pl] = __builtin_amdgcn_mfma_i32_32x32x32_i8(a1, b0, acc[0][1][pl], 0, 0, 0);
                acc[1][0][pl] = __builtin_amdgcn_mfma_i32_32x32x32_i8(a0, b1, acc[1][0][pl], 0, 0, 0);
                acc[1][1][pl] = __builtin_amdgcn_mfma_i32_32x32x32_i8(a1, b1, acc[1][1][pl], 0, 0, 0);
            }
        }
    }

    // ---- epilogue: combine planes, argmax over n in-register ----
#pragma unroll
    for (int sl = 0; sl < 2; ++sl) {
        float best = -3.0e38f;
        int   bestn = 0;
#pragma unroll
        for (int nh = 0; nh < 2; ++nh)
#pragma unroll
            for (int r = 0; r < 16; ++r) {
                float v = (float)acc[sl][nh][0][r] * 0.0078125f          // 2^-7
                        + (float)acc[sl][nh][1][r] * 6.103515625e-05f;   // 2^-14
                int n = nh * 32 + (r & 3) + 8 * (r >> 2) + 4 * h;
                if (v > best || (v == best && n < bestn)) { best = v; bestn = n; }
            }
        float ov = __shfl_xor(best, 32);
        int   on = __shfl_xor(bestn, 32);
        if (ov > best || (ov == best && on < bestn)) { best = ov; bestn = on; }
        const int u = u0 + 32 * (wid + 4 * sl) + col;
        if (h == 0 && u < U_TOTAL) {
            maxv[b * U_TOTAL + u] = best + HALF_TH;
            argn[b * U_TOTAL + u] = bestn;
        }
    }
}

// ---------------------------------------------------------------------------
// Kernel 4: grid-stride zero-fill of the int32 output (poisoned before every call).
// ---------------------------------------------------------------------------
__global__ __launch_bounds__(256) void zero_out(int* __restrict__ out, int n4) {
    int4 z4 = make_int4(0, 0, 0, 0);
    int4* o4 = (int4*)out;
    int stride = gridDim.x * 256;
    for (int i = blockIdx.x * 256 + threadIdx.x; i < n4; i += stride) o4[i] = z4;
}

// ---------------------------------------------------------------------------
// Kernel 5: WTA depression scan, ballot + mask-walk (wave per batch).
// spike <=> first t >= prev_spike+49 with maxv > THETA.
// ---------------------------------------------------------------------------
__global__ __launch_bounds__(64) void wta_kernel(const float* __restrict__ maxv,
                                                 const int*   __restrict__ argn,
                                                 int* __restrict__ out) {
    __shared__ int sarg[U_TOTAL];
    const int b   = blockIdx.x;
    const int tid = threadIdx.x;
    int* ob = out + (size_t)b * OUT_PER_B;

    for (int t = tid; t < U_TOTAL; t += 64)
        sarg[t] = argn[b * U_TOTAL + t];
    __syncthreads();

    int cur = 0;                                   // next allowed spike time (lane0 state)
#pragma unroll
    for (int c = 0; c < 17; ++c) {                 // 17*64 = 1088 >= 1081
        int t = c * 64 + tid;
        float mv = (t < U_TOTAL) ? maxv[b * U_TOTAL + t] : -1.0f;
        unsigned long long mask = __ballot(mv > THETA_F);
        if (tid == 0 && mask) {
            int base = c * 64;
            while (true) {
                int lo = cur - base;
                if (lo >= 64) break;
                if (lo < 0) lo = 0;
                unsigned long long m = mask >> lo;
                if (!m) break;
                int ts = base + lo + __builtin_ctzll(m);
                ob[sarg[ts] * U_TOTAL + ts] = 1;
                cur = ts + 49;                     // depression blocks 48 steps
            }
        }
    }
}

// ---------------------------------------------------------------------------
extern "C" void kernel_launch(void* const* d_in, const int* in_sizes, int n_in,
                              void* d_out, int out_size, void* d_ws, size_t ws_size,
                              hipStream_t stream) {
    const float* x      = (const float*)d_in[0];   // [128,1,256,1000]
    const float* weight = (const float*)d_in[1];   // [64,256]
    int* out = (int*)d_out;                        // [128,1,64,1081] int32

    char*  ws   = (char*)d_ws;
    char*  xT   = ws;                                          // 128*1328*40 = 6,799,360 (+2KB pad)
    char*  gtab = ws + ((size_t)128 * T_PAD * XROW + 2048);    // 1,572,864
    float* maxv = (float*)(gtab + (size_t)KJ * 2 * NEUR * 256);
    int*   argn = (int*)((char*)maxv + (size_t)128 * U_TOTAL * 4);

    hipLaunchKernelGGL(build_gtab_i8, dim3((KJ * 2 * NEUR * 256) / 256), dim3(256),
                       0, stream, weight, gtab);
    hipLaunchKernelGGL(build_xT, dim3((T_PAD + 31) / 32, 128), dim3(256),
                       0, stream, x, xT);
    hipLaunchKernelGGL(zero_out, dim3(2048), dim3(256),
                       0, stream, out, (128 * OUT_PER_B) / 4);
    hipLaunchKernelGGL(conv_i8, dim3((U_TOTAL + U_SPAN - 1) / U_SPAN, 128), dim3(256),
                       0, stream, xT, gtab, maxv, argn);
    hipLaunchKernelGGL(wta_kernel, dim3(128), dim3(64),
                       0, stream, maxv, argn, out);
}